// Round 1
// baseline (394.868 us; speedup 1.0000x reference)
//
#include <hip/hip_runtime.h>
#include <hip/hip_bf16.h>

#define B_ 8
#define S_ 1024
#define DIN 1024
#define HEADS 16
#define FILTERS 64
#define HF 1024

typedef __attribute__((ext_vector_type(8))) short bf16x8;
typedef __attribute__((ext_vector_type(4))) float f32x4;

__device__ __forceinline__ unsigned short f2bf(float f) {
  unsigned int u = __float_as_uint(f);
  u += 0x7fff + ((u >> 16) & 1);   // round-to-nearest-even
  return (unsigned short)(u >> 16);
}
__device__ __forceinline__ float bf2f(unsigned short h) {
  return __uint_as_float(((unsigned int)h) << 16);
}

// ---------------------------------------------------------------- prep
// WT[z][n][k] = W_z[k][n] as bf16 ; W1fT[f][c] = W1[c][f] + (c%64==f)
__global__ __launch_bounds__(256) void prep_weights(
    const float* __restrict__ Wq, const float* __restrict__ Wk,
    const float* __restrict__ Wv, const float* __restrict__ W1,
    unsigned short* __restrict__ WT, unsigned short* __restrict__ W1fT) {
  __shared__ float tl[64][65];
  int t = threadIdx.x;
  int z = blockIdx.y;
  if (z < 3) {
    const float* W = z == 0 ? Wq : (z == 1 ? Wk : Wv);
    unsigned short* out = WT + (size_t)z * 1024 * 1024;
    int k0 = (blockIdx.x >> 4) << 6;
    int n0 = (blockIdx.x & 15) << 6;
    for (int i = 0; i < 16; ++i) {
      int idx = t + i * 256; int r = idx >> 6, c = idx & 63;
      tl[r][c] = W[(size_t)(k0 + r) * HF + n0 + c];
    }
    __syncthreads();
    for (int i = 0; i < 16; ++i) {
      int idx = t + i * 256; int r = idx >> 6, c = idx & 63;
      out[(size_t)(n0 + r) * DIN + k0 + c] = f2bf(tl[c][r]);
    }
  } else {
    if (blockIdx.x >= 16) return;
    int k0 = blockIdx.x << 6;
    for (int i = 0; i < 16; ++i) {
      int idx = t + i * 256; int r = idx >> 6, c = idx & 63;
      tl[r][c] = W1[(size_t)(k0 + r) * FILTERS + c];
    }
    __syncthreads();
    for (int i = 0; i < 16; ++i) {
      int idx = t + i * 256; int f = idx >> 6, c = idx & 63;
      float v = tl[c][f] + ((((k0 + c) & 63) == f) ? 1.0f : 0.0f);
      W1fT[(size_t)f * HF + k0 + c] = f2bf(v);
    }
  }
}

// ---------------------------------------------------------------- QKV GEMM
// out[z] layout: [B][H][S][F] bf16, 128x128 tile, 4 waves, 16x16x32 MFMA
__global__ __launch_bounds__(256) void qkv_gemm(
    const float* __restrict__ Aq, const float* __restrict__ Ak,
    const float* __restrict__ Av, const unsigned short* __restrict__ WT,
    const float* __restrict__ bq, const float* __restrict__ bk,
    const float* __restrict__ bv, unsigned short* __restrict__ outq) {
  __shared__ char lsA[128 * 128];   // 128 rows x 64 bf16 (128B/row), XOR-swizzled
  __shared__ char lsB[128 * 128];
  int tid = threadIdx.x;
  int z = blockIdx.z;
  const float* A = z == 0 ? Aq : (z == 1 ? Ak : Av);
  const float* bias = z == 0 ? bq : (z == 1 ? bk : bv);
  const unsigned short* Bm = WT + (size_t)z * 1048576;
  unsigned short* out = outq + (size_t)z * 8388608;
  int bm = blockIdx.x, bn = blockIdx.y;
  int lane = tid & 63, wv = tid >> 6;
  int wr = wv >> 1, wc = wv & 1;
  f32x4 acc[4][4] = {};
  for (int k0 = 0; k0 < DIN; k0 += 64) {
    __syncthreads();
    // stage A (fp32 -> bf16)
    #pragma unroll
    for (int i = 0; i < 8; ++i) {
      int idx = tid + i * 256;             // 2048 float4 chunks
      int row = idx >> 4, c4 = idx & 15;
      float4 v = *(const float4*)(A + (size_t)(bm * 128 + row) * DIN + k0 + c4 * 4);
      ushort4 h;
      h.x = f2bf(v.x); h.y = f2bf(v.y); h.z = f2bf(v.z); h.w = f2bf(v.w);
      *(ushort4*)(lsA + row * 128 + ((c4 * 8) ^ ((row & 7) << 4))) = h;
    }
    // stage B (bf16 copy)
    #pragma unroll
    for (int i = 0; i < 4; ++i) {
      int idx = tid + i * 256;             // 1024 16B chunks
      int row = idx >> 3, c8 = idx & 7;
      int4 v = *(const int4*)(Bm + (size_t)(bn * 128 + row) * DIN + k0 + c8 * 8);
      *(int4*)(lsB + row * 128 + ((c8 * 16) ^ ((row & 7) << 4))) = v;
    }
    __syncthreads();
    #pragma unroll
    for (int kk = 0; kk < 2; ++kk) {
      int colb = kk * 64 + ((lane >> 4) << 4);
      bf16x8 af[4], bfr[4];
      #pragma unroll
      for (int m = 0; m < 4; ++m) {
        int row = wr * 64 + m * 16 + (lane & 15);
        af[m] = *(const bf16x8*)(lsA + row * 128 + (colb ^ ((row & 7) << 4)));
      }
      #pragma unroll
      for (int n = 0; n < 4; ++n) {
        int row = wc * 64 + n * 16 + (lane & 15);
        bfr[n] = *(const bf16x8*)(lsB + row * 128 + (colb ^ ((row & 7) << 4)));
      }
      #pragma unroll
      for (int m = 0; m < 4; ++m)
        #pragma unroll
        for (int n = 0; n < 4; ++n)
          acc[m][n] = __builtin_amdgcn_mfma_f32_16x16x32_bf16(af[m], bfr[n], acc[m][n], 0, 0, 0);
    }
  }
  // epilogue: +bias, write [B][H][S][F] bf16
  #pragma unroll
  for (int n = 0; n < 4; ++n) {
    int col = bn * 128 + wc * 64 + n * 16 + (lane & 15);
    float bb = bias[col];
    int h = col >> 6, f = col & 63;
    #pragma unroll
    for (int m = 0; m < 4; ++m)
      #pragma unroll
      for (int r = 0; r < 4; ++r) {
        int rowg = bm * 128 + wr * 64 + m * 16 + ((lane >> 4) << 2) + r;
        int b = rowg >> 10, s = rowg & 1023;
        out[(size_t)(((b * HEADS + h) << 10) + s) * 64 + f] = f2bf(acc[m][n][r] + bb);
      }
  }
}

// ---------------------------------------------------------------- V transpose
__global__ __launch_bounds__(256) void transpose_v(
    const unsigned short* __restrict__ v_bh, unsigned short* __restrict__ vT_bh) {
  __shared__ unsigned short tl[64][68];
  int t = threadIdx.x;
  int bh = blockIdx.y;
  int s0 = blockIdx.x << 6;
  const unsigned short* src = v_bh + ((size_t)bh * S_ + s0) * 64;
  #pragma unroll
  for (int i = 0; i < 2; ++i) {
    int idx = t + i * 256; int row = idx >> 3, c8 = idx & 7;
    int4 v = *(const int4*)(src + row * 64 + c8 * 8);
    const unsigned short* pv = (const unsigned short*)&v;
    #pragma unroll
    for (int e = 0; e < 8; ++e) tl[row][c8 * 8 + e] = pv[e];
  }
  __syncthreads();
  unsigned short* dst = vT_bh + (size_t)bh * 64 * S_;
  #pragma unroll
  for (int i = 0; i < 16; ++i) {
    int idx = t + i * 256; int f = idx >> 6, sl = idx & 63;
    dst[(size_t)f * S_ + s0 + sl] = tl[sl][f];
  }
}

// ---------------------------------------------------------------- attention
// grid (16 q-tiles, 128 bh); flash-style, 64-row Q tile, wave w owns 16 rows
__global__ __launch_bounds__(256) void attn_kernel(
    const unsigned short* __restrict__ q_bh, const unsigned short* __restrict__ k_bh,
    const unsigned short* __restrict__ vT_bh, float* __restrict__ en_f) {
  __shared__ char lsQ[64 * 128], lsK[64 * 128], lsV[64 * 128];
  __shared__ char lsP[4 * 16 * 128];
  int tid = threadIdx.x, lane = tid & 63, wv = tid >> 6;
  int bh = blockIdx.y; int b = bh >> 4, h = bh & 15;
  int s0 = blockIdx.x << 6;
  const unsigned short* qp = q_bh + ((size_t)bh * S_ + s0) * 64;
  #pragma unroll
  for (int i = 0; i < 2; ++i) {
    int idx = tid + i * 256; int row = idx >> 3, c8 = idx & 7;
    int4 v = *(const int4*)(qp + row * 64 + c8 * 8);
    *(int4*)(lsQ + row * 128 + ((c8 * 16) ^ ((row & 7) << 4))) = v;
  }
  __syncthreads();
  bf16x8 qf[2];
  {
    int row = wv * 16 + (lane & 15);
    #pragma unroll
    for (int kk = 0; kk < 2; ++kk) {
      int colb = kk * 64 + ((lane >> 4) << 4);
      qf[kk] = *(const bf16x8*)(lsQ + row * 128 + (colb ^ ((row & 7) << 4)));
    }
  }
  float m_run[4] = {-1e30f, -1e30f, -1e30f, -1e30f};
  float l_run[4] = {0.f, 0.f, 0.f, 0.f};
  f32x4 oacc[4] = {};
  for (int t = 0; t < 16; ++t) {
    __syncthreads();
    const unsigned short* kp = k_bh + ((size_t)bh * S_ + t * 64) * 64;
    #pragma unroll
    for (int i = 0; i < 2; ++i) {
      int idx = tid + i * 256; int row = idx >> 3, c8 = idx & 7;
      int4 v = *(const int4*)(kp + row * 64 + c8 * 8);
      *(int4*)(lsK + row * 128 + ((c8 * 16) ^ ((row & 7) << 4))) = v;
    }
    const unsigned short* vp = vT_bh + (size_t)bh * 64 * S_ + t * 64;
    #pragma unroll
    for (int i = 0; i < 2; ++i) {
      int idx = tid + i * 256; int row = idx >> 3, c8 = idx & 7;   // row = f
      int4 v = *(const int4*)(vp + (size_t)row * S_ + c8 * 8);
      *(int4*)(lsV + row * 128 + ((c8 * 16) ^ ((row & 7) << 4))) = v;
    }
    __syncthreads();
    f32x4 sacc[4] = {};
    #pragma unroll
    for (int kk = 0; kk < 2; ++kk) {
      int colb = kk * 64 + ((lane >> 4) << 4);
      #pragma unroll
      for (int j = 0; j < 4; ++j) {
        int row = j * 16 + (lane & 15);
        bf16x8 kf = *(const bf16x8*)(lsK + row * 128 + (colb ^ ((row & 7) << 4)));
        sacc[j] = __builtin_amdgcn_mfma_f32_16x16x32_bf16(qf[kk], kf, sacc[j], 0, 0, 0);
      }
    }
    float mnew[4], resc[4], psum[4];
    #pragma unroll
    for (int r = 0; r < 4; ++r) {
      float mx = -1e30f;
      #pragma unroll
      for (int j = 0; j < 4; ++j) { sacc[j][r] *= 0.125f; mx = fmaxf(mx, sacc[j][r]); }
      mx = fmaxf(mx, __shfl_xor(mx, 1));
      mx = fmaxf(mx, __shfl_xor(mx, 2));
      mx = fmaxf(mx, __shfl_xor(mx, 4));
      mx = fmaxf(mx, __shfl_xor(mx, 8));
      mnew[r] = fmaxf(m_run[r], mx);
      resc[r] = __expf(m_run[r] - mnew[r]);
      m_run[r] = mnew[r];
      psum[r] = 0.f;
    }
    #pragma unroll
    for (int j = 0; j < 4; ++j)
      #pragma unroll
      for (int r = 0; r < 4; ++r) {
        float p = __expf(sacc[j][r] - mnew[r]);
        sacc[j][r] = p;
        psum[r] += p;
      }
    char* pbase = lsP + wv * 2048;
    #pragma unroll
    for (int r = 0; r < 4; ++r) {
      float ps = psum[r];
      ps += __shfl_xor(ps, 1);
      ps += __shfl_xor(ps, 2);
      ps += __shfl_xor(ps, 4);
      ps += __shfl_xor(ps, 8);
      l_run[r] = l_run[r] * resc[r] + ps;
      #pragma unroll
      for (int j = 0; j < 4; ++j) oacc[j][r] *= resc[r];
      int row = ((lane >> 4) << 2) + r;
      int swz = (row & 7) << 4;
      #pragma unroll
      for (int j = 0; j < 4; ++j) {
        int cb = (j * 32 + ((lane & 15) << 1)) ^ swz;
        *(unsigned short*)(pbase + row * 128 + cb) = f2bf(sacc[j][r]);
      }
    }
    __syncthreads();   // make P visible (also orders within-wave write->read)
    #pragma unroll
    for (int kk = 0; kk < 2; ++kk) {
      int colb = kk * 64 + ((lane >> 4) << 4);
      int prow = lane & 15;
      bf16x8 pa = *(const bf16x8*)(pbase + prow * 128 + (colb ^ ((prow & 7) << 4)));
      #pragma unroll
      for (int j = 0; j < 4; ++j) {
        int row = j * 16 + (lane & 15);
        bf16x8 vf = *(const bf16x8*)(lsV + row * 128 + (colb ^ ((row & 7) << 4)));
        oacc[j] = __builtin_amdgcn_mfma_f32_16x16x32_bf16(pa, vf, oacc[j], 0, 0, 0);
      }
    }
  }
  #pragma unroll
  for (int r = 0; r < 4; ++r) {
    float inv = 1.0f / l_run[r];
    int qrow = wv * 16 + ((lane >> 4) << 2) + r;
    int s = s0 + qrow;
    float* op = en_f + ((size_t)(b * S_ + s)) * HF + h * 64;
    #pragma unroll
    for (int j = 0; j < 4; ++j) {
      int cb = ((j * 32 + ((lane & 15) << 1)) ^ ((qrow & 7) << 4));
      float qv = bf2f(*(const unsigned short*)(lsQ + qrow * 128 + cb));
      op[j * 16 + (lane & 15)] = oacc[j][r] * inv + qv;
    }
  }
}

// ---------------------------------------------------------------- GroupNorm1
__global__ __launch_bounds__(256) void gn1_stats(
    const float* __restrict__ en_f, float* __restrict__ gsum, float* __restrict__ gss) {
  int b = blockIdx.x >> 2;
  int c = ((blockIdx.x & 3) << 8) + threadIdx.x;
  int s0 = blockIdx.y << 7;
  float sum = 0.f, ss = 0.f;
  const float* p = en_f + ((size_t)(b << 10) + s0) * 1024 + c;
  for (int i = 0; i < 128; ++i) {
    float x = p[(size_t)i * 1024];
    sum += x; ss += x * x;
  }
  atomicAdd(&gsum[b * 1024 + c], sum);
  atomicAdd(&gss[b * 1024 + c], ss);
}

__global__ __launch_bounds__(256) void gn1_norm(
    const float* __restrict__ en_f, const float* __restrict__ gsum,
    const float* __restrict__ gss, unsigned short* __restrict__ enf0) {
  const float invS = 1.0f / 1024.0f;
  int gs = gridDim.x * blockDim.x;
  for (size_t i = (size_t)blockIdx.x * 256 + threadIdx.x; i < (size_t)2097152; i += gs) {
    float4 x = ((const float4*)en_f)[i];
    size_t lin = i * 4;
    int c = (int)(lin & 1023);
    int b = (int)(lin >> 20);
    float vals[4] = {x.x, x.y, x.z, x.w};
    unsigned short o[4];
    #pragma unroll
    for (int e = 0; e < 4; ++e) {
      float mean = gsum[b * 1024 + c + e] * invS;
      float var = gss[b * 1024 + c + e] * invS - mean * mean;
      float rstd = rsqrtf(var + 1e-3f);
      o[e] = f2bf((vals[e] - mean) * rstd);
    }
    ushort4 y = {o[0], o[1], o[2], o[3]};
    ((ushort4*)enf0)[i] = y;
  }
}

// ---------------------------------------------------------------- dense (+folded head-sum)
__global__ __launch_bounds__(256) void dense_kernel(
    const unsigned short* __restrict__ enf0, const unsigned short* __restrict__ W1fT,
    const float* __restrict__ b1, float* __restrict__ out1) {
  __shared__ char lsA[64 * 128], lsB[64 * 128];
  int tid = threadIdx.x, lane = tid & 63, wv = tid >> 6;
  int bm = blockIdx.x;
  f32x4 acc[4] = {};
  for (int k0 = 0; k0 < HF; k0 += 64) {
    __syncthreads();
    #pragma unroll
    for (int i = 0; i < 2; ++i) {
      int idx = tid + i * 256; int row = idx >> 3, c8 = idx & 7;
      int4 v = *(const int4*)(enf0 + (size_t)(bm * 64 + row) * HF + k0 + c8 * 8);
      *(int4*)(lsA + row * 128 + ((c8 * 16) ^ ((row & 7) << 4))) = v;
    }
    #pragma unroll
    for (int i = 0; i < 2; ++i) {
      int idx = tid + i * 256; int row = idx >> 3, c8 = idx & 7;
      int4 v = *(const int4*)(W1fT + (size_t)row * HF + k0 + c8 * 8);
      *(int4*)(lsB + row * 128 + ((c8 * 16) ^ ((row & 7) << 4))) = v;
    }
    __syncthreads();
    #pragma unroll
    for (int kk = 0; kk < 2; ++kk) {
      int colb = kk * 64 + ((lane >> 4) << 4);
      int arow = wv * 16 + (lane & 15);
      bf16x8 af = *(const bf16x8*)(lsA + arow * 128 + (colb ^ ((arow & 7) << 4)));
      #pragma unroll
      for (int j = 0; j < 4; ++j) {
        int row = j * 16 + (lane & 15);
        bf16x8 bfr = *(const bf16x8*)(lsB + row * 128 + (colb ^ ((row & 7) << 4)));
        acc[j] = __builtin_amdgcn_mfma_f32_16x16x32_bf16(af, bfr, acc[j], 0, 0, 0);
      }
    }
  }
  #pragma unroll
  for (int j = 0; j < 4; ++j) {
    int f = j * 16 + (lane & 15);
    float bb = b1[f];
    #pragma unroll
    for (int r = 0; r < 4; ++r) {
      int rowg = bm * 64 + wv * 16 + ((lane >> 4) << 2) + r;
      out1[(size_t)rowg * 64 + f] = acc[j][r] + bb;
    }
  }
}

// ---------------------------------------------------------------- GroupNorm2
__global__ __launch_bounds__(256) void gn2_stats(
    const float* __restrict__ out1, float* __restrict__ g2sum, float* __restrict__ g2ss) {
  __shared__ float r1[256], r2[256];
  int t = threadIdx.x;
  int b = blockIdx.y;
  int s0 = blockIdx.x << 6;
  int f = t & 63, sl = t >> 6;
  float sum = 0.f, ss = 0.f;
  for (int i = 0; i < 16; ++i) {
    int s = s0 + sl + i * 4;
    float x = out1[((size_t)(b << 10) + s) * 64 + f];
    sum += x; ss += x * x;
  }
  r1[t] = sum; r2[t] = ss;
  __syncthreads();
  if (t < 64) {
    sum = r1[t] + r1[t + 64] + r1[t + 128] + r1[t + 192];
    ss  = r2[t] + r2[t + 64] + r2[t + 128] + r2[t + 192];
    atomicAdd(&g2sum[b * 64 + t], sum);
    atomicAdd(&g2ss[b * 64 + t], ss);
  }
}

__global__ __launch_bounds__(256) void gn2_norm(
    const float* __restrict__ out1, const float* __restrict__ g2sum,
    const float* __restrict__ g2ss, float* __restrict__ dout) {
  const float invS = 1.0f / 1024.0f;
  int gs = gridDim.x * blockDim.x;
  for (int i = blockIdx.x * 256 + threadIdx.x; i < 131072; i += gs) {
    float4 x = ((const float4*)out1)[i];
    int lin = i * 4;
    int f = lin & 63;
    int b = lin >> 16;
    float vals[4] = {x.x, x.y, x.z, x.w};
    float o[4];
    #pragma unroll
    for (int e = 0; e < 4; ++e) {
      float mean = g2sum[b * 64 + f + e] * invS;
      float var = g2ss[b * 64 + f + e] * invS - mean * mean;
      float rstd = rsqrtf(var + 1e-3f);
      o[e] = (vals[e] - mean) * rstd;
    }
    float4 y = {o[0], o[1], o[2], o[3]};
    ((float4*)dout)[i] = y;
  }
}

// ---------------------------------------------------------------- launch
extern "C" void kernel_launch(void* const* d_in, const int* in_sizes, int n_in,
                              void* d_out, int out_size, void* d_ws, size_t ws_size,
                              hipStream_t stream) {
  const float* qw = (const float*)d_in[0];
  const float* kw = (const float*)d_in[1];
  const float* vw = (const float*)d_in[2];
  const float* Wq = (const float*)d_in[3];
  const float* bq = (const float*)d_in[4];
  const float* Wk = (const float*)d_in[5];
  const float* bk = (const float*)d_in[6];
  const float* Wv = (const float*)d_in[7];
  const float* bv = (const float*)d_in[8];
  const float* W1 = (const float*)d_in[9];
  const float* b1 = (const float*)d_in[10];

  char* ws = (char*)d_ws;
  unsigned short* WT   = (unsigned short*)(ws);                  // 6 MB
  unsigned short* W1fT = (unsigned short*)(ws + 6291456);        // 128 KB
  unsigned short* qb   = (unsigned short*)(ws + 6422528);        // q,k,v: 3 x 16 MB
  unsigned short* vT   = (unsigned short*)(ws + 56754176);       // 16 MB
  float* en_f          = (float*)(ws + 73531392);                // 32 MB
  unsigned short* enf0 = (unsigned short*)(ws + 107085824);      // 16 MB
  float* gsum          = (float*)(ws + 123863040);               // 32 KB
  float* gss           = (float*)(ws + 123895808);               // 32 KB
  float* out1          = (float*)(ws + 123928576);               // 2 MB
  float* g2sum         = (float*)(ws + 126025728);               // 2 KB
  float* g2ss          = (float*)(ws + 126027776);               // 2 KB

  hipMemsetAsync(gsum, 0, 65536, stream);   // gsum + gss
  hipMemsetAsync(g2sum, 0, 4096, stream);   // g2sum + g2ss

  prep_weights<<<dim3(256, 4), 256, 0, stream>>>(Wq, Wk, Wv, W1, WT, W1fT);
  qkv_gemm<<<dim3(64, 8, 3), 256, 0, stream>>>(qw, kw, vw, WT, bq, bk, bv, qb);
  transpose_v<<<dim3(16, 128), 256, 0, stream>>>(qb + 2 * 8388608, vT);
  attn_kernel<<<dim3(16, 128), 256, 0, stream>>>(qb, qb + 8388608, vT, en_f);
  gn1_stats<<<dim3(32, 8), 256, 0, stream>>>(en_f, gsum, gss);
  gn1_norm<<<2048, 256, 0, stream>>>(en_f, gsum, gss, enf0);
  dense_kernel<<<128, 256, 0, stream>>>(enf0, W1fT, b1, out1);
  gn2_stats<<<dim3(16, 8), 256, 0, stream>>>(out1, g2sum, g2ss);
  gn2_norm<<<512, 256, 0, stream>>>(out1, g2sum, g2ss, (float*)d_out);
}